// Round 10
// baseline (451.715 us; speedup 1.0000x reference)
//
#include <hip/hip_runtime.h>
#include <stdint.h>

// SuperpointGenerator v19: v17 + straggler/search trims. Round-9 lesson:
// empty-bucket early-outs were neutral because K4/K6 duration is set by the
// BIGGEST (central) buckets — load imbalance, not aggregate bytes.
// (1) LPT ordering: blockIdx.x -> bucket via center-out permutation so big
//     central buckets launch first, empties backfill the tail.
// (2) K8: binary search (9-10 divergent LDS steps/point) replaced by
//     radix-range probe: first[id>>11] built via LDS atomicMin (1024 slots,
//     ~1.15 entries/slot), then 1-2 sorted-scan loads. Bit-identical.
// Pipeline:
//   Kz zero_cur     : zero 2432 cursors
//   K1 vidx_sort    : coords -> vlo/vhi + LDS count/sort + reserve + u16 runs
//   K4 bucket_hist  : per-bucket LDS count -> 256-bin hist + cnt16k dump
//   K5 select_params: T, A=#{c>T}, m, per-bucket winner/tier bases
//   K6 collect2     : cnt16k scan -> winners (c>T) + id-ordered tier (c==T)
//   K7 rank512      : rank by (count desc, id asc) -> packed lookup
//   K8 write_labels4: radix-range probe of packed table, planar in / int4 out

#define BATCHES 32
#define NPTS    (1 << 18)
#define MAX_SP  512
#define NBUK    76
#define BUK_VOX 16384
#define DRANGE  (NBUK * BUK_VOX)     // 1245184
#define OFFSET  (DRANGE / 2)         // 622592
#define BUK_DW  (BUK_VOX / 4)        // 4096
#define TIERCAP 18432
#define BPB     64                   // blocks per batch in K1/K8
#define PPB     (NPTS / BPB)         // 4096 points per block
#define CAP     32768                // u16 slots per (batch,bucket) segment

typedef float    f32x4 __attribute__((ext_vector_type(4)));
typedef int      i32x4 __attribute__((ext_vector_type(4)));
typedef uint32_t u32x4 __attribute__((ext_vector_type(4)));
typedef uint32_t u32x2 __attribute__((ext_vector_type(2)));
typedef uint16_t u16x4 __attribute__((ext_vector_type(4)));

__device__ __forceinline__ int pidx(float x, float y, float z) {
    int vx = (int)(x / 0.2f);        // IEEE f32 divide + trunc-to-zero == ref
    int vy = (int)(y / 0.2f);
    int vz = (int)(z / 0.2f);
    int id = vx * 10000 + vy * 100 + vz;
    int idx = id + OFFSET;
    idx = idx < 0 ? 0 : (idx >= DRANGE ? DRANGE - 1 : idx);  // memory safety only
    return idx;
}

// center-out bucket permutation: big (central) buckets first (LPT schedule)
__device__ __forceinline__ int lpt_bucket(int i) {
    return (i & 1) ? (38 + (i >> 1)) : (37 - (i >> 1));   // bijection on [0,76)
}

// ---- Kz: zero per-(batch,bucket) reservation cursors ----
__global__ void __launch_bounds__(1024) zero_cur(int* __restrict__ gcur)
{
    int i = blockIdx.x * 1024 + threadIdx.x;
    if (i < BATCHES * NBUK) gcur[i] = 0;
}

// ---- K1: coords -> vlo/vhi + LDS counting sort + atomic reserve + u16 runs ----
__global__ void __launch_bounds__(1024) vidx_sort(
    const float* __restrict__ coords, uint16_t* __restrict__ vlo,
    uint8_t* __restrict__ vhi, int* __restrict__ gcur,
    uint16_t* __restrict__ lists)
{
    int b = blockIdx.x >> 6, blk = blockIdx.x & 63, tid = threadIdx.x;
    __shared__ int cnt[NBUK];
    __shared__ int stage[PPB];       // 16 KB: points sorted by bucket
    __shared__ int offs[NBUK];       // within-block exclusive prefix
    __shared__ int cur[NBUK];        // LDS scatter cursors
    __shared__ int rebase[NBUK];     // (k*CAP + reserved) - offs[k]
    if (tid < NBUK) cnt[tid] = 0;
    __syncthreads();
    size_t p0 = (size_t)b * NPTS + (size_t)blk * PPB + (size_t)tid * 4;
    const f32x4* cp = (const f32x4*)(coords + p0 * 3);   // 48 B, 16B-aligned
    f32x4 a = __builtin_nontemporal_load(cp + 0);
    f32x4 c = __builtin_nontemporal_load(cp + 1);
    f32x4 d = __builtin_nontemporal_load(cp + 2);
    i32x4 iv;
    iv[0] = pidx(a[0], a[1], a[2]);
    iv[1] = pidx(a[3], c[0], c[1]);
    iv[2] = pidx(c[2], c[3], d[0]);
    iv[3] = pidx(d[1], d[2], d[3]);
    // planar 3-byte store: u16 lows (8 B) + packed u8 highs (4 B)
    u32x2 lo;
    lo[0] = ((uint32_t)iv[0] & 0xFFFFu) | ((uint32_t)iv[1] << 16);
    lo[1] = ((uint32_t)iv[2] & 0xFFFFu) | ((uint32_t)iv[3] << 16);
    uint32_t hi = ((uint32_t)iv[0] >> 16) | (((uint32_t)iv[1] >> 16) << 8) |
                  (((uint32_t)iv[2] >> 16) << 16) | (((uint32_t)iv[3] >> 16) << 24);
    __builtin_nontemporal_store(lo, (u32x2*)(vlo + p0));
    __builtin_nontemporal_store(hi, (uint32_t*)(vhi + p0));
    atomicAdd(&cnt[iv[0] >> 14], 1);
    atomicAdd(&cnt[iv[1] >> 14], 1);
    atomicAdd(&cnt[iv[2] >> 14], 1);
    atomicAdd(&cnt[iv[3] >> 14], 1);
    __syncthreads();
    if (tid == 0) {
        int run = 0;
        for (int k = 0; k < NBUK; ++k) { offs[k] = run; run += cnt[k]; }
    }
    __syncthreads();
    if (tid < NBUK) {
        cur[tid] = offs[tid];
        int base = atomicAdd(&gcur[b * NBUK + tid], cnt[tid]);  // reserve range
        rebase[tid] = (tid * CAP + base) - offs[tid];
    }
    __syncthreads();
    #pragma unroll
    for (int j = 0; j < 4; ++j) {
        int idx = iv[j];
        stage[atomicAdd(&cur[idx >> 14], 1)] = idx;
    }
    __syncthreads();
    uint16_t* lb = lists + (size_t)b * (NBUK * CAP);
    #pragma unroll
    for (int j = 0; j < 4; ++j) {
        int i = j * 1024 + tid;      // lane-consecutive -> coalesced runs
        int v = stage[i];
        __builtin_nontemporal_store((uint16_t)(v & (BUK_VOX - 1)),
                                    &lb[rebase[v >> 14] + i]);
    }
}

// ---- K4: per-(batch,bucket) LDS count -> 256-bin hist + cnt16k dump ----
__global__ void __launch_bounds__(1024) bucket_hist(
    const uint16_t* __restrict__ lists, const int* __restrict__ gcur,
    int* __restrict__ bhist, uint32_t* __restrict__ cnt16k)
{
    int k = lpt_bucket(blockIdx.x), b = blockIdx.y, tid = threadIdx.x;
    int n = gcur[b * NBUK + k];          // final cursor = bucket total
    if (n == 0) {                        // empty bucket: zero bhist, skip rest
        if (tid < 256) bhist[((size_t)b * NBUK + k) * 256 + tid] = 0;
        return;                          // cnt16k left unwritten; K6 skips
    }
    __shared__ uint32_t cnt[BUK_DW];     // 16 KB
    __shared__ uint32_t h8[8 * 256];     // 8 KB
    for (int i = tid; i < BUK_DW; i += 1024) cnt[i] = 0;
    for (int i = tid; i < 8 * 256; i += 1024) h8[i] = 0;
    __syncthreads();
    const uint16_t* seg = lists + (size_t)b * (NBUK * CAP) + (size_t)k * CAP;
    int nv = (n + 3) >> 2;               // u16x4 chunks (8 B/lane)
    for (int i = tid; i < nv; i += 1024) {
        u16x4 v4 = ((const u16x4*)seg)[i];   // seg 64KB-aligned; in-CAP always
        int base = i * 4;
        #pragma unroll
        for (int j = 0; j < 4; ++j) {
            if (base + j < n) {          // guard: tail beyond n is unwritten
                int idx = v4[j];
                atomicAdd(&cnt[idx >> 2], 1u << ((idx & 3) * 8));
            }
        }
    }
    __syncthreads();
    // thread t owns dwords [4t,4t+4): hist update + coalesced dump (regular
    // store -> stays L2/L3 resident for K6)
    u32x4 w4 = ((const u32x4*)cnt)[tid];
    ((u32x4*)(cnt16k + (size_t)(b * NBUK + k) * BUK_DW))[tid] = w4;
    int rep = (tid >> 7) & 7;
    #pragma unroll
    for (int d = 0; d < 4; ++d) {
        uint32_t w = w4[d];
        if (!w) continue;
        #pragma unroll
        for (int j = 0; j < 4; ++j) {
            uint32_t cc = (w >> (j * 8)) & 255u;
            if (cc) atomicAdd(&h8[rep * 256 + cc], 1u);
        }
    }
    __syncthreads();
    if (tid < 256) {
        uint32_t s = 0;
        #pragma unroll
        for (int r = 0; r < 8; ++r) s += h8[r * 256 + tid];
        bhist[((size_t)b * NBUK + k) * 256 + tid] = (int)s;
    }
}

// ---- K5: derive T/A/m/nu and per-bucket winner/tier exclusive bases ----
__global__ void __launch_bounds__(256) select_params(
    const int* __restrict__ bhist, int* __restrict__ params,
    int* __restrict__ wbase, int* __restrict__ tbase)
{
    int b = blockIdx.x, tid = threadIdx.x;
    __shared__ int tot[256];
    __shared__ int wc_[NBUK], tc_[NBUK];
    __shared__ int sh_T;
    int s = 0;
    for (int k = 0; k < NBUK; ++k) s += bhist[((size_t)b * NBUK + k) * 256 + tid];
    tot[tid] = s;
    __syncthreads();
    if (tid == 0) {
        int nu = 0;
        for (int c = 1; c < 256; ++c) nu += tot[c];
        int acc = 0, c = 255;
        while (c > 1 && acc + tot[c] < MAX_SP) { acc += tot[c]; --c; }
        int T = c, A = acc;
        int m = MAX_SP - A; if (m > tot[T]) m = tot[T];   // nu<=512: whole tier
        params[b * 8 + 0] = T;  params[b * 8 + 1] = A;
        params[b * 8 + 2] = m;  params[b * 8 + 3] = nu;
        params[b * 8 + 4] = A + m;                        // nw = min(512, nu)
        sh_T = T;
    }
    __syncthreads();
    int T = sh_T;
    if (tid < NBUK) {
        int ws = 0;
        const int* bh = bhist + ((size_t)b * NBUK + tid) * 256;
        for (int c = T + 1; c < 256; ++c) ws += bh[c];
        wc_[tid] = ws;
        tc_[tid] = bh[T];
    }
    __syncthreads();
    if (tid == 0) {
        int aw = 0, at = 0;
        for (int k = 0; k < NBUK; ++k) {
            wbase[b * NBUK + k] = aw; tbase[b * NBUK + k] = at;
            aw += wc_[k]; at += tc_[k];
        }
    }
}

// ---- K6: cnt16k scan -> winners (any order) + tier (exact id order) ----
__global__ void __launch_bounds__(512) collect2(
    const uint32_t* __restrict__ cnt16k, const int* __restrict__ gcur,
    const int* __restrict__ params, const int* __restrict__ wbase,
    const int* __restrict__ tbase, uint32_t* __restrict__ wid,
    int* __restrict__ wcnt, uint32_t* __restrict__ tier)
{
    int k = lpt_bucket(blockIdx.x), b = blockIdx.y, tid = threadIdx.x;
    if (gcur[b * NBUK + k] == 0) return;   // empty bucket (block-uniform)
    int T = params[b * 8 + 0], m = params[b * 8 + 2];
    int wb = wbase[b * NBUK + k], tb = tbase[b * NBUK + k];
    __shared__ int woff[8];
    __shared__ int wpos;
    if (tid == 0) wpos = 0;
    // per-thread CONTIGUOUS 8 dwords: id order within thread, tid asc
    const u32x4* g = (const u32x4*)(cnt16k + (size_t)(b * NBUK + k) * BUK_DW);
    u32x4 v[2];
    v[0] = g[tid * 2 + 0];
    v[1] = g[tid * 2 + 1];
    __syncthreads();                 // wpos visible
    int base_id = (k * BUK_DW + tid * 8) * 4;
    int ntier = 0;
    #pragma unroll
    for (int q = 0; q < 2; ++q) {
        #pragma unroll
        for (int d = 0; d < 4; ++d) {
            uint32_t w = v[q][d];
            if (!w) continue;
            #pragma unroll
            for (int j = 0; j < 4; ++j) {
                int c = (int)((w >> (j * 8)) & 255u);
                if (c > T) {
                    int p = atomicAdd(&wpos, 1);
                    wid [b * MAX_SP + wb + p] = (uint32_t)(base_id + (q * 4 + d) * 4 + j);
                    wcnt[b * MAX_SP + wb + p] = c;
                } else if (c == T) ++ntier;
            }
        }
    }
    // block exclusive scan of ntier: shfl wave scan + 8-wave offset pass
    int lane = tid & 63, wv = tid >> 6;
    int inc = ntier;
    #pragma unroll
    for (int s = 1; s < 64; s <<= 1) {
        int y = __shfl_up(inc, s);
        if (lane >= s) inc += y;
    }
    if (lane == 63) woff[wv] = inc;
    __syncthreads();
    int pre = inc - ntier;
    for (int i = 0; i < wv; ++i) pre += woff[i];
    if (tb < m && ntier > 0) {           // only blocks that can hold tier[0..m)
        int pos = tb + pre, kk = 0;
        #pragma unroll
        for (int q = 0; q < 2; ++q) {
            #pragma unroll
            for (int d = 0; d < 4; ++d) {
                uint32_t w = v[q][d];
                if (!w) continue;
                #pragma unroll
                for (int j = 0; j < 4; ++j) {
                    int c = (int)((w >> (j * 8)) & 255u);
                    if (c == T) {
                        int q2 = pos + kk; ++kk;
                        if (q2 < TIERCAP) tier[b * TIERCAP + q2] = (uint32_t)(base_id + (q * 4 + d) * 4 + j);
                    }
                }
            }
        }
    }
}

// ---- K7: rank 512 winners; emit PACKED table (idx<<9 | label), sorted by idx ----
__global__ void __launch_bounds__(512) rank512(
    const int* __restrict__ params, const uint32_t* __restrict__ wid,
    const int* __restrict__ wcnt, const uint32_t* __restrict__ tier,
    uint32_t* __restrict__ lookup)
{
    int b = blockIdx.x, tid = threadIdx.x;
    int T = params[b * 8 + 0], A = params[b * 8 + 1];
    int nu = params[b * 8 + 3], nw = params[b * 8 + 4];
    __shared__ uint32_t wu[MAX_SP];
    __shared__ int      wc[MAX_SP];
    if (tid < A)       { wu[tid] = wid[b * MAX_SP + tid]; wc[tid] = wcnt[b * MAX_SP + tid]; }
    else if (tid < nw) { wu[tid] = tier[b * TIERCAP + (tid - A)]; wc[tid] = T; }
    __syncthreads();
    if (tid < nw) {
        uint32_t u = wu[tid]; int c = wc[tid];
        int r = 0, ur = 0;
        for (int j = 0; j < nw; ++j) {
            uint32_t uj = wu[j]; int cj = wc[j];
            r  += ((cj > c) || (cj == c && uj < u)) ? 1 : 0;
            ur += (uj < u) ? 1 : 0;
        }
        int label = (nu <= MAX_SP) ? ur : r;               // inverse branch: id-rank
        lookup[b * MAX_SP + ur] = (u << 9) | (uint32_t)label;   // idx 21b | label 9b
    }
}

// ---- K8: label 4 pts/thread via radix-range probe; planar vlo/vhi in ----
__global__ void __launch_bounds__(1024) write_labels4(
    const uint16_t* __restrict__ vlo, const uint8_t* __restrict__ vhi,
    const int* __restrict__ params, const uint32_t* __restrict__ lookup,
    int* __restrict__ out)
{
    __shared__ uint32_t lu[MAX_SP];
    __shared__ int first[1024];      // first entry with id>>11 == h (or INF)
    int b = blockIdx.x >> 6, tid = threadIdx.x;
    if (tid < MAX_SP) lu[tid] = lookup[b * MAX_SP + tid];
    first[tid] = 0x7FFFFFFF;
    __syncthreads();
    int nw = params[b * 8 + 4];
    if (tid < nw) atomicMin(&first[lu[tid] >> 20], tid);   // id>>11 == lu>>20
    __syncthreads();
    size_t p0 = (size_t)b * NPTS + (size_t)(blockIdx.x & 63) * PPB + (size_t)tid * 4;
    u32x2 lo = __builtin_nontemporal_load((const u32x2*)(vlo + p0));
    uint32_t hi = __builtin_nontemporal_load((const uint32_t*)(vhi + p0));
    uint32_t us[4];
    us[0] = (lo[0] & 0xFFFFu) | ((hi & 0xFFu) << 16);
    us[1] = (lo[0] >> 16)     | (((hi >> 8) & 0xFFu) << 16);
    us[2] = (lo[1] & 0xFFFFu) | (((hi >> 16) & 0xFFu) << 16);
    us[3] = (lo[1] >> 16)     | ((hi >> 24) << 16);
    i32x4 ov;
    #pragma unroll
    for (int j = 0; j < 4; ++j) {
        uint32_t u = us[j];
        uint32_t h = u >> 11;
        int label = 0;
        int t = first[h];
        if (t < nw) {
            for (; t < nw; ++t) {        // entries sorted by id; same-h run
                uint32_t e = lu[t];
                uint32_t eid = e >> 9;
                if ((eid >> 11) != h || eid > u) break;
                if (eid == u) { label = (int)(e & 511u); break; }
            }
        }
        ov[j] = label;
    }
    __builtin_nontemporal_store(ov, (i32x4*)(out + p0));
}

extern "C" void kernel_launch(void* const* d_in, const int* in_sizes, int n_in,
                              void* d_out, int out_size, void* d_ws, size_t ws_size,
                              hipStream_t stream) {
    const float* coords = (const float*)d_in[0];
    int* out = (int*)d_out;

    uint8_t* p = (uint8_t*)d_ws;
    uint16_t* vlo     = (uint16_t*)p; p += (size_t)BATCHES * NPTS * 2;          // 16.8 MB
    uint8_t*  vhi     = (uint8_t*)p;  p += (size_t)BATCHES * NPTS;              // 8.4 MB
    uint16_t* lists   = (uint16_t*)p; p += (size_t)BATCHES * NBUK * CAP * 2;    // 159.4 MB
    uint32_t* cnt16k  = (uint32_t*)p; p += (size_t)BATCHES * NBUK * BUK_DW * 4; // 39.8 MB
    int*      gcur    = (int*)p;      p += (size_t)BATCHES * NBUK * 4;
    int*      bhist   = (int*)p;      p += (size_t)BATCHES * NBUK * 256 * 4;    // 2.5 MB
    uint32_t* tier    = (uint32_t*)p; p += (size_t)BATCHES * TIERCAP * 4;       // 2.4 MB
    int*      wbase   = (int*)p;      p += (size_t)BATCHES * NBUK * 4;
    int*      tbase   = (int*)p;      p += (size_t)BATCHES * NBUK * 4;
    int*      params  = (int*)p;      p += (size_t)BATCHES * 8 * 4;
    uint32_t* wid     = (uint32_t*)p; p += (size_t)BATCHES * MAX_SP * 4;
    int*      wcnt    = (int*)p;      p += (size_t)BATCHES * MAX_SP * 4;
    uint32_t* lookup  = (uint32_t*)p; p += (size_t)BATCHES * MAX_SP * 4;

    zero_cur     <<<3, 1024, 0, stream>>>(gcur);
    vidx_sort    <<<BATCHES * BPB, 1024, 0, stream>>>(coords, vlo, vhi, gcur, lists);
    bucket_hist  <<<dim3(NBUK, BATCHES), 1024, 0, stream>>>(lists, gcur, bhist, cnt16k);
    select_params<<<BATCHES, 256, 0, stream>>>(bhist, params, wbase, tbase);
    collect2     <<<dim3(NBUK, BATCHES), 512, 0, stream>>>(cnt16k, gcur, params, wbase, tbase, wid, wcnt, tier);
    rank512      <<<BATCHES, 512, 0, stream>>>(params, wid, wcnt, tier, lookup);
    write_labels4<<<BATCHES * BPB, 1024, 0, stream>>>(vlo, vhi, params, lookup, out);
}

// Round 12
// 288.574 us; speedup vs baseline: 1.5653x; 1.5653x over previous
//
#include <hip/hip_runtime.h>
#include <stdint.h>

// SuperpointGenerator v20b: identical to v20 (round-11 bench was an infra
// failure — "container failed twice", no counters; no kernel change could
// explain it: every component ran in rounds 8-10). K8 = v17's proven binary
// search; LPT bucket permutation kept from v19 (ran fine in round 10).
// Pipeline:
//   Kz zero_cur     : zero 2432 cursors
//   K1 vidx_sort    : coords -> vlo/vhi + LDS count/sort + reserve + u16 runs
//   K4 bucket_hist  : per-bucket LDS count -> 256-bin hist + cnt16k dump
//   K5 select_params: T, A=#{c>T}, m, per-bucket winner/tier bases
//   K6 collect2     : cnt16k scan -> winners (c>T) + id-ordered tier (c==T)
//   K7 rank512      : rank by (count desc, id asc) -> packed lookup
//   K8 write_labels4: binary-search packed table, planar in / int4 out

#define BATCHES 32
#define NPTS    (1 << 18)
#define MAX_SP  512
#define NBUK    76
#define BUK_VOX 16384
#define DRANGE  (NBUK * BUK_VOX)     // 1245184
#define OFFSET  (DRANGE / 2)         // 622592
#define BUK_DW  (BUK_VOX / 4)        // 4096
#define TIERCAP 18432
#define BPB     64                   // blocks per batch in K1/K8
#define PPB     (NPTS / BPB)         // 4096 points per block
#define CAP     32768                // u16 slots per (batch,bucket) segment

typedef float    f32x4 __attribute__((ext_vector_type(4)));
typedef int      i32x4 __attribute__((ext_vector_type(4)));
typedef uint32_t u32x4 __attribute__((ext_vector_type(4)));
typedef uint32_t u32x2 __attribute__((ext_vector_type(2)));
typedef uint16_t u16x4 __attribute__((ext_vector_type(4)));

__device__ __forceinline__ int pidx(float x, float y, float z) {
    int vx = (int)(x / 0.2f);        // IEEE f32 divide + trunc-to-zero == ref
    int vy = (int)(y / 0.2f);
    int vz = (int)(z / 0.2f);
    int id = vx * 10000 + vy * 100 + vz;
    int idx = id + OFFSET;
    idx = idx < 0 ? 0 : (idx >= DRANGE ? DRANGE - 1 : idx);  // memory safety only
    return idx;
}

// center-out bucket permutation: big (central) buckets first (LPT schedule)
__device__ __forceinline__ int lpt_bucket(int i) {
    return (i & 1) ? (38 + (i >> 1)) : (37 - (i >> 1));   // bijection on [0,76)
}

// ---- Kz: zero per-(batch,bucket) reservation cursors ----
__global__ void __launch_bounds__(1024) zero_cur(int* __restrict__ gcur)
{
    int i = blockIdx.x * 1024 + threadIdx.x;
    if (i < BATCHES * NBUK) gcur[i] = 0;
}

// ---- K1: coords -> vlo/vhi + LDS counting sort + atomic reserve + u16 runs ----
__global__ void __launch_bounds__(1024) vidx_sort(
    const float* __restrict__ coords, uint16_t* __restrict__ vlo,
    uint8_t* __restrict__ vhi, int* __restrict__ gcur,
    uint16_t* __restrict__ lists)
{
    int b = blockIdx.x >> 6, blk = blockIdx.x & 63, tid = threadIdx.x;
    __shared__ int cnt[NBUK];
    __shared__ int stage[PPB];       // 16 KB: points sorted by bucket
    __shared__ int offs[NBUK];       // within-block exclusive prefix
    __shared__ int cur[NBUK];        // LDS scatter cursors
    __shared__ int rebase[NBUK];     // (k*CAP + reserved) - offs[k]
    if (tid < NBUK) cnt[tid] = 0;
    __syncthreads();
    size_t p0 = (size_t)b * NPTS + (size_t)blk * PPB + (size_t)tid * 4;
    const f32x4* cp = (const f32x4*)(coords + p0 * 3);   // 48 B, 16B-aligned
    f32x4 a = __builtin_nontemporal_load(cp + 0);
    f32x4 c = __builtin_nontemporal_load(cp + 1);
    f32x4 d = __builtin_nontemporal_load(cp + 2);
    i32x4 iv;
    iv[0] = pidx(a[0], a[1], a[2]);
    iv[1] = pidx(a[3], c[0], c[1]);
    iv[2] = pidx(c[2], c[3], d[0]);
    iv[3] = pidx(d[1], d[2], d[3]);
    // planar 3-byte store: u16 lows (8 B) + packed u8 highs (4 B)
    u32x2 lo;
    lo[0] = ((uint32_t)iv[0] & 0xFFFFu) | ((uint32_t)iv[1] << 16);
    lo[1] = ((uint32_t)iv[2] & 0xFFFFu) | ((uint32_t)iv[3] << 16);
    uint32_t hi = ((uint32_t)iv[0] >> 16) | (((uint32_t)iv[1] >> 16) << 8) |
                  (((uint32_t)iv[2] >> 16) << 16) | (((uint32_t)iv[3] >> 16) << 24);
    __builtin_nontemporal_store(lo, (u32x2*)(vlo + p0));
    __builtin_nontemporal_store(hi, (uint32_t*)(vhi + p0));
    atomicAdd(&cnt[iv[0] >> 14], 1);
    atomicAdd(&cnt[iv[1] >> 14], 1);
    atomicAdd(&cnt[iv[2] >> 14], 1);
    atomicAdd(&cnt[iv[3] >> 14], 1);
    __syncthreads();
    if (tid == 0) {
        int run = 0;
        for (int k = 0; k < NBUK; ++k) { offs[k] = run; run += cnt[k]; }
    }
    __syncthreads();
    if (tid < NBUK) {
        cur[tid] = offs[tid];
        int base = atomicAdd(&gcur[b * NBUK + tid], cnt[tid]);  // reserve range
        rebase[tid] = (tid * CAP + base) - offs[tid];
    }
    __syncthreads();
    #pragma unroll
    for (int j = 0; j < 4; ++j) {
        int idx = iv[j];
        stage[atomicAdd(&cur[idx >> 14], 1)] = idx;
    }
    __syncthreads();
    uint16_t* lb = lists + (size_t)b * (NBUK * CAP);
    #pragma unroll
    for (int j = 0; j < 4; ++j) {
        int i = j * 1024 + tid;      // lane-consecutive -> coalesced runs
        int v = stage[i];
        __builtin_nontemporal_store((uint16_t)(v & (BUK_VOX - 1)),
                                    &lb[rebase[v >> 14] + i]);
    }
}

// ---- K4: per-(batch,bucket) LDS count -> 256-bin hist + cnt16k dump ----
__global__ void __launch_bounds__(1024) bucket_hist(
    const uint16_t* __restrict__ lists, const int* __restrict__ gcur,
    int* __restrict__ bhist, uint32_t* __restrict__ cnt16k)
{
    int k = lpt_bucket(blockIdx.x), b = blockIdx.y, tid = threadIdx.x;
    int n = gcur[b * NBUK + k];          // final cursor = bucket total
    if (n == 0) {                        // empty bucket: zero bhist, skip rest
        if (tid < 256) bhist[((size_t)b * NBUK + k) * 256 + tid] = 0;
        return;                          // cnt16k left unwritten; K6 skips
    }
    __shared__ uint32_t cnt[BUK_DW];     // 16 KB
    __shared__ uint32_t h8[8 * 256];     // 8 KB
    for (int i = tid; i < BUK_DW; i += 1024) cnt[i] = 0;
    for (int i = tid; i < 8 * 256; i += 1024) h8[i] = 0;
    __syncthreads();
    const uint16_t* seg = lists + (size_t)b * (NBUK * CAP) + (size_t)k * CAP;
    int nv = (n + 3) >> 2;               // u16x4 chunks (8 B/lane)
    for (int i = tid; i < nv; i += 1024) {
        u16x4 v4 = ((const u16x4*)seg)[i];   // seg 64KB-aligned; in-CAP always
        int base = i * 4;
        #pragma unroll
        for (int j = 0; j < 4; ++j) {
            if (base + j < n) {          // guard: tail beyond n is unwritten
                int idx = v4[j];
                atomicAdd(&cnt[idx >> 2], 1u << ((idx & 3) * 8));
            }
        }
    }
    __syncthreads();
    // thread t owns dwords [4t,4t+4): hist update + coalesced dump (regular
    // store -> stays L2/L3 resident for K6)
    u32x4 w4 = ((const u32x4*)cnt)[tid];
    ((u32x4*)(cnt16k + (size_t)(b * NBUK + k) * BUK_DW))[tid] = w4;
    int rep = (tid >> 7) & 7;
    #pragma unroll
    for (int d = 0; d < 4; ++d) {
        uint32_t w = w4[d];
        if (!w) continue;
        #pragma unroll
        for (int j = 0; j < 4; ++j) {
            uint32_t cc = (w >> (j * 8)) & 255u;
            if (cc) atomicAdd(&h8[rep * 256 + cc], 1u);
        }
    }
    __syncthreads();
    if (tid < 256) {
        uint32_t s = 0;
        #pragma unroll
        for (int r = 0; r < 8; ++r) s += h8[r * 256 + tid];
        bhist[((size_t)b * NBUK + k) * 256 + tid] = (int)s;
    }
}

// ---- K5: derive T/A/m/nu and per-bucket winner/tier exclusive bases ----
__global__ void __launch_bounds__(256) select_params(
    const int* __restrict__ bhist, int* __restrict__ params,
    int* __restrict__ wbase, int* __restrict__ tbase)
{
    int b = blockIdx.x, tid = threadIdx.x;
    __shared__ int tot[256];
    __shared__ int wc_[NBUK], tc_[NBUK];
    __shared__ int sh_T;
    int s = 0;
    for (int k = 0; k < NBUK; ++k) s += bhist[((size_t)b * NBUK + k) * 256 + tid];
    tot[tid] = s;
    __syncthreads();
    if (tid == 0) {
        int nu = 0;
        for (int c = 1; c < 256; ++c) nu += tot[c];
        int acc = 0, c = 255;
        while (c > 1 && acc + tot[c] < MAX_SP) { acc += tot[c]; --c; }
        int T = c, A = acc;
        int m = MAX_SP - A; if (m > tot[T]) m = tot[T];   // nu<=512: whole tier
        params[b * 8 + 0] = T;  params[b * 8 + 1] = A;
        params[b * 8 + 2] = m;  params[b * 8 + 3] = nu;
        params[b * 8 + 4] = A + m;                        // nw = min(512, nu)
        sh_T = T;
    }
    __syncthreads();
    int T = sh_T;
    if (tid < NBUK) {
        int ws = 0;
        const int* bh = bhist + ((size_t)b * NBUK + tid) * 256;
        for (int c = T + 1; c < 256; ++c) ws += bh[c];
        wc_[tid] = ws;
        tc_[tid] = bh[T];
    }
    __syncthreads();
    if (tid == 0) {
        int aw = 0, at = 0;
        for (int k = 0; k < NBUK; ++k) {
            wbase[b * NBUK + k] = aw; tbase[b * NBUK + k] = at;
            aw += wc_[k]; at += tc_[k];
        }
    }
}

// ---- K6: cnt16k scan -> winners (any order) + tier (exact id order) ----
__global__ void __launch_bounds__(512) collect2(
    const uint32_t* __restrict__ cnt16k, const int* __restrict__ gcur,
    const int* __restrict__ params, const int* __restrict__ wbase,
    const int* __restrict__ tbase, uint32_t* __restrict__ wid,
    int* __restrict__ wcnt, uint32_t* __restrict__ tier)
{
    int k = lpt_bucket(blockIdx.x), b = blockIdx.y, tid = threadIdx.x;
    if (gcur[b * NBUK + k] == 0) return;   // empty bucket (block-uniform)
    int T = params[b * 8 + 0], m = params[b * 8 + 2];
    int wb = wbase[b * NBUK + k], tb = tbase[b * NBUK + k];
    __shared__ int woff[8];
    __shared__ int wpos;
    if (tid == 0) wpos = 0;
    // per-thread CONTIGUOUS 8 dwords: id order within thread, tid asc
    const u32x4* g = (const u32x4*)(cnt16k + (size_t)(b * NBUK + k) * BUK_DW);
    u32x4 v[2];
    v[0] = g[tid * 2 + 0];
    v[1] = g[tid * 2 + 1];
    __syncthreads();                 // wpos visible
    int base_id = (k * BUK_DW + tid * 8) * 4;
    int ntier = 0;
    #pragma unroll
    for (int q = 0; q < 2; ++q) {
        #pragma unroll
        for (int d = 0; d < 4; ++d) {
            uint32_t w = v[q][d];
            if (!w) continue;
            #pragma unroll
            for (int j = 0; j < 4; ++j) {
                int c = (int)((w >> (j * 8)) & 255u);
                if (c > T) {
                    int p = atomicAdd(&wpos, 1);
                    wid [b * MAX_SP + wb + p] = (uint32_t)(base_id + (q * 4 + d) * 4 + j);
                    wcnt[b * MAX_SP + wb + p] = c;
                } else if (c == T) ++ntier;
            }
        }
    }
    // block exclusive scan of ntier: shfl wave scan + 8-wave offset pass
    int lane = tid & 63, wv = tid >> 6;
    int inc = ntier;
    #pragma unroll
    for (int s = 1; s < 64; s <<= 1) {
        int y = __shfl_up(inc, s);
        if (lane >= s) inc += y;
    }
    if (lane == 63) woff[wv] = inc;
    __syncthreads();
    int pre = inc - ntier;
    for (int i = 0; i < wv; ++i) pre += woff[i];
    if (tb < m && ntier > 0) {           // only blocks that can hold tier[0..m)
        int pos = tb + pre, kk = 0;
        #pragma unroll
        for (int q = 0; q < 2; ++q) {
            #pragma unroll
            for (int d = 0; d < 4; ++d) {
                uint32_t w = v[q][d];
                if (!w) continue;
                #pragma unroll
                for (int j = 0; j < 4; ++j) {
                    int c = (int)((w >> (j * 8)) & 255u);
                    if (c == T) {
                        int q2 = pos + kk; ++kk;
                        if (q2 < TIERCAP) tier[b * TIERCAP + q2] = (uint32_t)(base_id + (q * 4 + d) * 4 + j);
                    }
                }
            }
        }
    }
}

// ---- K7: rank 512 winners; emit PACKED table (idx<<9 | label), sorted by idx ----
__global__ void __launch_bounds__(512) rank512(
    const int* __restrict__ params, const uint32_t* __restrict__ wid,
    const int* __restrict__ wcnt, const uint32_t* __restrict__ tier,
    uint32_t* __restrict__ lookup)
{
    int b = blockIdx.x, tid = threadIdx.x;
    int T = params[b * 8 + 0], A = params[b * 8 + 1];
    int nu = params[b * 8 + 3], nw = params[b * 8 + 4];
    __shared__ uint32_t wu[MAX_SP];
    __shared__ int      wc[MAX_SP];
    if (tid < A)       { wu[tid] = wid[b * MAX_SP + tid]; wc[tid] = wcnt[b * MAX_SP + tid]; }
    else if (tid < nw) { wu[tid] = tier[b * TIERCAP + (tid - A)]; wc[tid] = T; }
    __syncthreads();
    if (tid < nw) {
        uint32_t u = wu[tid]; int c = wc[tid];
        int r = 0, ur = 0;
        for (int j = 0; j < nw; ++j) {
            uint32_t uj = wu[j]; int cj = wc[j];
            r  += ((cj > c) || (cj == c && uj < u)) ? 1 : 0;
            ur += (uj < u) ? 1 : 0;
        }
        int label = (nu <= MAX_SP) ? ur : r;               // inverse branch: id-rank
        lookup[b * MAX_SP + ur] = (u << 9) | (uint32_t)label;   // idx 21b | label 9b
    }
}

// ---- K8: label 4 pts/thread via binary search; planar vlo/vhi in ----
__global__ void __launch_bounds__(1024) write_labels4(
    const uint16_t* __restrict__ vlo, const uint8_t* __restrict__ vhi,
    const int* __restrict__ params, const uint32_t* __restrict__ lookup,
    int* __restrict__ out)
{
    __shared__ uint32_t lu[MAX_SP];
    int b = blockIdx.x >> 6, tid = threadIdx.x;
    if (tid < MAX_SP) lu[tid] = lookup[b * MAX_SP + tid];
    __syncthreads();
    int nw = params[b * 8 + 4];
    size_t p0 = (size_t)b * NPTS + (size_t)(blockIdx.x & 63) * PPB + (size_t)tid * 4;
    u32x2 lo = __builtin_nontemporal_load((const u32x2*)(vlo + p0));
    uint32_t hi = __builtin_nontemporal_load((const uint32_t*)(vhi + p0));
    uint32_t us[4];
    us[0] = (lo[0] & 0xFFFFu) | ((hi & 0xFFu) << 16);
    us[1] = (lo[0] >> 16)     | (((hi >> 8) & 0xFFu) << 16);
    us[2] = (lo[1] & 0xFFFFu) | (((hi >> 16) & 0xFFu) << 16);
    us[3] = (lo[1] >> 16)     | ((hi >> 24) << 16);
    i32x4 ov;
    #pragma unroll
    for (int j = 0; j < 4; ++j) {
        uint32_t u = us[j];
        int lo_ = 0, hi_ = nw;
        while (lo_ < hi_) { int mid = (lo_ + hi_) >> 1; if ((lu[mid] >> 9) < u) lo_ = mid + 1; else hi_ = mid; }
        int label = 0;
        if (lo_ < nw && (lu[lo_] >> 9) == u) label = (int)(lu[lo_] & 511u);
        ov[j] = label;
    }
    __builtin_nontemporal_store(ov, (i32x4*)(out + p0));
}

extern "C" void kernel_launch(void* const* d_in, const int* in_sizes, int n_in,
                              void* d_out, int out_size, void* d_ws, size_t ws_size,
                              hipStream_t stream) {
    const float* coords = (const float*)d_in[0];
    int* out = (int*)d_out;

    uint8_t* p = (uint8_t*)d_ws;
    uint16_t* vlo     = (uint16_t*)p; p += (size_t)BATCHES * NPTS * 2;          // 16.8 MB
    uint8_t*  vhi     = (uint8_t*)p;  p += (size_t)BATCHES * NPTS;              // 8.4 MB
    uint16_t* lists   = (uint16_t*)p; p += (size_t)BATCHES * NBUK * CAP * 2;    // 159.4 MB
    uint32_t* cnt16k  = (uint32_t*)p; p += (size_t)BATCHES * NBUK * BUK_DW * 4; // 39.8 MB
    int*      gcur    = (int*)p;      p += (size_t)BATCHES * NBUK * 4;
    int*      bhist   = (int*)p;      p += (size_t)BATCHES * NBUK * 256 * 4;    // 2.5 MB
    uint32_t* tier    = (uint32_t*)p; p += (size_t)BATCHES * TIERCAP * 4;       // 2.4 MB
    int*      wbase   = (int*)p;      p += (size_t)BATCHES * NBUK * 4;
    int*      tbase   = (int*)p;      p += (size_t)BATCHES * NBUK * 4;
    int*      params  = (int*)p;      p += (size_t)BATCHES * 8 * 4;
    uint32_t* wid     = (uint32_t*)p; p += (size_t)BATCHES * MAX_SP * 4;
    int*      wcnt    = (int*)p;      p += (size_t)BATCHES * MAX_SP * 4;
    uint32_t* lookup  = (uint32_t*)p; p += (size_t)BATCHES * MAX_SP * 4;

    zero_cur     <<<3, 1024, 0, stream>>>(gcur);
    vidx_sort    <<<BATCHES * BPB, 1024, 0, stream>>>(coords, vlo, vhi, gcur, lists);
    bucket_hist  <<<dim3(NBUK, BATCHES), 1024, 0, stream>>>(lists, gcur, bhist, cnt16k);
    select_params<<<BATCHES, 256, 0, stream>>>(bhist, params, wbase, tbase);
    collect2     <<<dim3(NBUK, BATCHES), 512, 0, stream>>>(cnt16k, gcur, params, wbase, tbase, wid, wcnt, tier);
    rank512      <<<BATCHES, 512, 0, stream>>>(params, wid, wcnt, tier, lookup);
    write_labels4<<<BATCHES * BPB, 1024, 0, stream>>>(vlo, vhi, params, lookup, out);
}